// Round 1
// baseline (257.576 us; speedup 1.0000x reference)
//
#include <hip/hip_runtime.h>

// Problem constants (from reference setup_inputs):
//   spike_seq: (T=1024, B=16384, 2) fp32; w_exc: (1,2); w_inh: scalar.
// Outputs concatenated flat: spk_rec (T*B) then mem_rec (T*B), fp32.
#define T_LEN 1024
#define B_N   16384
#define UNROLL 16   // prefetch depth: 16 outstanding 8B loads/lane = 8KiB/wave in flight

// One thread per neuron; sequential over T (reset nonlinearity forbids
// parallel scan). 256 blocks x 64 threads = 1 wave/CU across all 256 CUs;
// latency hidden by explicit double-buffered prefetch (ILP, not TLP).
__global__ __launch_bounds__(64, 1) void FMFMNeuronInhib_34033320854098_kernel(
    const float* __restrict__ x,      // (T, B, 2)
    const float* __restrict__ w_exc,  // 2 elements: {0.7, 1.0}
    const float* __restrict__ w_inh,  // 1 element: -1.0
    float* __restrict__ out) {
  // No FMA contraction: must round mul/add separately to bit-match the
  // numpy reference — a 1-ulp mem difference at the threshold flips a spike.
#pragma clang fp contract(off)
  const int b = blockIdx.x * 64 + threadIdx.x;
  const float w0 = w_exc[0];
  const float w1 = w_exc[1];
  const float wi = w_inh[0];

  float* __restrict__ spk_out = out;                          // [T*B]
  float* __restrict__ mem_out = out + (size_t)T_LEN * B_N;    // [T*B]
  const float2* __restrict__ xp = (const float2*)x;           // T*B float2, coalesced per t

  float mem = 0.0f;
  float inh = 0.0f;

  float2 cur_buf[UNROLL];
  float2 nxt_buf[UNROLL];

  // Prime the pipeline: loads for t = 0..UNROLL-1.
#pragma unroll
  for (int u = 0; u < UNROLL; ++u) cur_buf[u] = xp[u * B_N + b];

  for (int t0 = 0; t0 < T_LEN; t0 += UNROLL) {
    const int t1 = t0 + UNROLL;
    // Issue next batch's loads before consuming the current batch, so
    // UNROLL global_load_dwordx2 stay in flight during the state updates.
    if (t1 < T_LEN) {
#pragma unroll
      for (int u = 0; u < UNROLL; ++u) nxt_buf[u] = xp[(t1 + u) * B_N + b];
    }
#pragma unroll
    for (int u = 0; u < UNROLL; ++u) {
      const int t = t0 + u;
      const float x0 = cur_buf[u].x;
      const float x1 = cur_buf[u].y;
      // cur_exc = x @ w_exc^T  (w1 = 1.0 -> exact)
      const float cur_exc = x0 * w0 + x1 * w1;
      // inh = 0.6*inh + x0
      inh = 0.6f * inh + x0;
      // cur = cur_exc + w_inh*inh  (wi = -1.0 -> exact negation)
      const float cur = cur_exc + wi * inh;
      // reset from PREVIOUS mem
      const float reset = (mem - 1.0f > 0.0f) ? 1.0f : 0.0f;
      // mem = 0.9*mem + cur - reset*1.0
      mem = 0.9f * mem + cur - reset * 1.0f;
      const float spk = (mem - 1.0f > 0.0f) ? 1.0f : 0.0f;
      spk_out[t * B_N + b] = spk;
      mem_out[t * B_N + b] = mem;
    }
#pragma unroll
    for (int u = 0; u < UNROLL; ++u) cur_buf[u] = nxt_buf[u];
  }
}

extern "C" void kernel_launch(void* const* d_in, const int* in_sizes, int n_in,
                              void* d_out, int out_size, void* d_ws, size_t ws_size,
                              hipStream_t stream) {
  const float* x     = (const float*)d_in[0];  // spike_seq, T*B*2 floats
  const float* w_exc = (const float*)d_in[1];  // 2 floats
  const float* w_inh = (const float*)d_in[2];  // 1 float
  float* out = (float*)d_out;                  // spk_rec ++ mem_rec

  dim3 grid(B_N / 64);  // 256 blocks -> 1 block (1 wave) per CU
  dim3 block(64);
  hipLaunchKernelGGL(FMFMNeuronInhib_34033320854098_kernel, grid, block, 0, stream,
                     x, w_exc, w_inh, out);
}